// Round 4
// baseline (3418.804 us; speedup 1.0000x reference)
//
#include <hip/hip_runtime.h>
#include <math.h>

#define Bn 8
#define Cn 64
#define Hn 96
#define Wn 96
#define HWn (Hn*Wn)
#define OCn 64
#define Kn 9
#define OFFCn 27
#define NPIX (Bn*HWn)        // 73728 = 1152*64
#define PGRPS (NPIX/64)      // 1152 pixel groups
#define CSPL 8               // channel split in K2
#define CPW  (Cn/CSPL)       // 8 channels per wave chunk

// ws layout: float pwbuf[36][NPIX] then int abuf[9][NPIX] = 45*NPIX dwords
#define WS_DWORDS (45*NPIX)
#define WS_BYTES  ((size_t)WS_DWORDS*4)   // 13.27 MB

// ============================ K1: offsets + params + bias-init ================
__global__ __launch_bounds__(256, 2) void dcn_k1(
    const float* __restrict__ x,
    const float* __restrict__ w_off,
    const float* __restrict__ b_off,
    const float* __restrict__ bias,
    float* __restrict__ out,
    float* __restrict__ pwbuf,
    int*   __restrict__ abuf)
{
    __shared__ float lds[4 * 64 * OFFCn];   // 27.6 KB

    const int tid  = threadIdx.x;
    const int lane = tid & 63;
    const int wv   = tid >> 6;

    const int p  = blockIdx.x * 64 + lane;   // natural order (no XCD swizzle)
    const int b  = p / HWn;
    const int hw = p % HWn;
    const int ho = hw / Wn;
    const int wo = hw % Wn;

    const float* xb = x + b * (Cn * HWn);

    // static 3x3 taps, zero-pad via multiply
    int   toff[Kn];
    float tval[Kn];
#pragma unroll
    for (int ki = 0; ki < Kn; ++ki) {
        const int yy = ho + ki / 3 - 1, xx = wo + ki % 3 - 1;
        const bool v = (yy >= 0) && (yy < Hn) && (xx >= 0) && (xx < Wn);
        toff[ki] = min(max(yy, 0), Hn - 1) * Wn + min(max(xx, 0), Wn - 1);
        tval[ki] = v ? 1.0f : 0.0f;
    }

    // offset conv partial over 16 channels per wave
    float om[OFFCn];
#pragma unroll
    for (int j = 0; j < OFFCn; ++j) om[j] = 0.0f;

    for (int ci = 0; ci < 16; ++ci) {
        const int c = wv * 16 + ci;
        const float* xc = xb + c * HWn;
        float xk[Kn];
#pragma unroll
        for (int ki = 0; ki < Kn; ++ki)
            xk[ki] = xc[toff[ki]] * tval[ki];

        const float* wc = w_off + c * Kn;
#pragma unroll
        for (int och = 0; och < OFFCn; ++och) {
            const float* wp = wc + och * (Cn * Kn);
            float a = om[och];
#pragma unroll
            for (int ki = 0; ki < Kn; ++ki)
                a = fmaf(xk[ki], wp[ki], a);
            om[och] = a;
        }
    }

    // LDS reduce (stride 27, gcd(27,32)=1 -> conflict-free)
#pragma unroll
    for (int j = 0; j < OFFCn; ++j)
        lds[(wv * 64 + lane) * OFFCn + j] = om[j];
    __syncthreads();
#pragma unroll
    for (int j = 0; j < OFFCn; ++j) {
        float a = b_off[j];
#pragma unroll
        for (int ww = 0; ww < 4; ++ww)
            a += lds[(ww * 64 + lane) * OFFCn + j];
        om[j] = a;
    }

    // per-k sampling params (each wave computes redundantly; stores split)
    float pw0[Kn], pw1[Kn], pw2[Kn], pw3[Kn];
    int   pav[Kn];
#pragma unroll
    for (int ki = 0; ki < Kn; ++ki) {
        const float py = om[ki]      + (float)(ki / 3 + ho - 1);
        const float px = om[Kn + ki] + (float)(ki % 3 + wo - 1);
        const float m  = 1.0f / (1.0f + __expf(-om[2 * Kn + ki]));

        const float y0f = floorf(py), x0f = floorf(px);
        const float ly = py - y0f, lx = px - x0f;
        const int iy0 = (int)y0f, ix0 = (int)x0f;
        const int iy1 = iy0 + 1,  ix1 = ix0 + 1;

        const float vy0 = (iy0 >= 0 && iy0 < Hn) ? 1.0f : 0.0f;
        const float vy1 = (iy1 >= 0 && iy1 < Hn) ? 1.0f : 0.0f;
        const float vx0 = (ix0 >= 0 && ix0 < Wn) ? 1.0f : 0.0f;
        const float vx1 = (ix1 >= 0 && ix1 < Wn) ? 1.0f : 0.0f;

        const int iy0c = min(max(iy0, 0), Hn - 1);
        const int iy1c = min(max(iy1, 0), Hn - 1);
        const int ix0c = min(max(ix0, 0), Wn - 1);
        const int ix1c = min(max(ix1, 0), Wn - 1);

        pw0[ki] = m * (1.0f - ly) * (1.0f - lx) * vy0 * vx0;
        pw1[ki] = m * (1.0f - ly) * lx          * vy0 * vx1;
        pw2[ki] = m * ly          * (1.0f - lx) * vy1 * vx0;
        pw3[ki] = m * ly          * lx          * vy1 * vx1;
        const int pa  = iy0c * Wn + ix0c;        // <= 9215, fits 16 bits
        const int dx  = ix1c - ix0c;             // 0/1
        const int dyw = (iy1c - iy0c) * Wn;      // 0/96
        pav[ki] = pa | (dx << 16) | (dyw << 17);
    }

    // store params: wave wv stores pw{wv}; wave 0 also stores abuf
    if (wv == 0) {
#pragma unroll
        for (int ki = 0; ki < Kn; ++ki) pwbuf[(0 * Kn + ki) * NPIX + p] = pw0[ki];
#pragma unroll
        for (int ki = 0; ki < Kn; ++ki) abuf[ki * NPIX + p] = pav[ki];
    } else if (wv == 1) {
#pragma unroll
        for (int ki = 0; ki < Kn; ++ki) pwbuf[(1 * Kn + ki) * NPIX + p] = pw1[ki];
    } else if (wv == 2) {
#pragma unroll
        for (int ki = 0; ki < Kn; ++ki) pwbuf[(2 * Kn + ki) * NPIX + p] = pw2[ki];
    } else {
#pragma unroll
        for (int ki = 0; ki < Kn; ++ki) pwbuf[(3 * Kn + ki) * NPIX + p] = pw3[ki];
    }

    // bias init (overwrites poison every call; K2 atomics accumulate on top)
    float* ob = out + b * (OCn * HWn) + (wv * 16) * HWn + hw;
#pragma unroll
    for (int j = 0; j < 16; ++j)
        ob[j * HWn] = bias[wv * 16 + j];
}

// ============================ K2: sample + contract (c-split, atomic) =========
__global__ __launch_bounds__(256, 2) void dcn_k2(
    const float* __restrict__ x,
    const float* __restrict__ weight,
    const float* __restrict__ pwbuf,
    const int*   __restrict__ abuf,
    float* __restrict__ out)
{
    const int tid  = threadIdx.x;
    const int lane = tid & 63;
    const int wv   = tid >> 6;

    const int pg = blockIdx.x >> 1;                 // 0..1151
    const int cs = ((blockIdx.x & 1) << 2) | wv;    // 0..7
    const int p  = pg * 64 + lane;
    const int b  = p / HWn;
    const int hw = p % HWn;

    const float* xb = x + (b * Cn + cs * CPW) * HWn;

    // load params (all coalesced across lanes)
    float pw0[Kn], pw1[Kn], pw2[Kn], pw3[Kn];
    int   pa[Kn], pdx[Kn], pdyw[Kn];
#pragma unroll
    for (int ki = 0; ki < Kn; ++ki) pw0[ki] = pwbuf[(0 * Kn + ki) * NPIX + p];
#pragma unroll
    for (int ki = 0; ki < Kn; ++ki) pw1[ki] = pwbuf[(1 * Kn + ki) * NPIX + p];
#pragma unroll
    for (int ki = 0; ki < Kn; ++ki) pw2[ki] = pwbuf[(2 * Kn + ki) * NPIX + p];
#pragma unroll
    for (int ki = 0; ki < Kn; ++ki) pw3[ki] = pwbuf[(3 * Kn + ki) * NPIX + p];
#pragma unroll
    for (int ki = 0; ki < Kn; ++ki) {
        const int av = abuf[ki * NPIX + p];
        pa[ki]   = av & 0xFFFF;
        pdx[ki]  = (av >> 16) & 1;
        pdyw[ki] = av >> 17;
    }

    float acc[OCn];
#pragma unroll
    for (int oc = 0; oc < OCn; ++oc) acc[oc] = 0.0f;

#pragma unroll 2
    for (int c = 0; c < CPW; ++c) {
        const float* xc = xb + c * HWn;
        float s[Kn];
#pragma unroll
        for (int ki = 0; ki < Kn; ++ki) {
            const float* bp = xc + pa[ki];
            const float v00 = bp[0];
            const float v01 = bp[pdx[ki]];
            const float v10 = bp[pdyw[ki]];
            const float v11 = bp[pdyw[ki] + pdx[ki]];
            s[ki] = pw0[ki] * v00 + pw1[ki] * v01 + pw2[ki] * v10 + pw3[ki] * v11;
        }

        const float* wc = weight + (cs * CPW + c) * Kn;   // wave-uniform
#pragma unroll
        for (int oc = 0; oc < OCn; ++oc) {
            const float* wp = wc + oc * (Cn * Kn);
            float a = acc[oc];
#pragma unroll
            for (int ki = 0; ki < Kn; ++ki)
                a = fmaf(s[ki], wp[ki], a);
            acc[oc] = a;
        }
    }

    float* ob = out + b * (OCn * HWn) + hw;
#pragma unroll
    for (int oc = 0; oc < OCn; ++oc)
        atomicAdd(&ob[oc * HWn], acc[oc]);
}

// ============================ fallback (R1 single-kernel, if ws too small) ====
__global__ __launch_bounds__(64) void dcn_r1(
    const float* __restrict__ x,
    const float* __restrict__ w_off,
    const float* __restrict__ b_off,
    const float* __restrict__ weight,
    const float* __restrict__ bias,
    float* __restrict__ out)
{
    const int p  = blockIdx.x * 64 + threadIdx.x;
    const int b  = p / HWn;
    const int hw = p % HWn;
    const int ho = hw / Wn;
    const int wo = hw % Wn;
    const float* xb = x + b * (Cn * HWn);

    float om[OFFCn];
#pragma unroll
    for (int j = 0; j < OFFCn; ++j) om[j] = b_off[j];

    int   toff[Kn];
    float tval[Kn];
#pragma unroll
    for (int ki = 0; ki < Kn; ++ki) {
        const int yy = ho + ki / 3 - 1, xx = wo + ki % 3 - 1;
        const bool v = (yy >= 0) && (yy < Hn) && (xx >= 0) && (xx < Wn);
        toff[ki] = min(max(yy, 0), Hn - 1) * Wn + min(max(xx, 0), Wn - 1);
        tval[ki] = v ? 1.0f : 0.0f;
    }
    for (int c = 0; c < Cn; ++c) {
        const float* xc = xb + c * HWn;
        float xk[Kn];
#pragma unroll
        for (int ki = 0; ki < Kn; ++ki) xk[ki] = xc[toff[ki]] * tval[ki];
        const float* wc = w_off + c * Kn;
#pragma unroll
        for (int och = 0; och < OFFCn; ++och) {
            const float* wp = wc + och * (Cn * Kn);
            float a = om[och];
#pragma unroll
            for (int ki = 0; ki < Kn; ++ki) a = fmaf(xk[ki], wp[ki], a);
            om[och] = a;
        }
    }
    float pw0[Kn], pw1[Kn], pw2[Kn], pw3[Kn];
    int   pa[Kn], pdx[Kn], pdyw[Kn];
#pragma unroll
    for (int ki = 0; ki < Kn; ++ki) {
        const float py = om[ki]      + (float)(ki / 3 + ho - 1);
        const float px = om[Kn + ki] + (float)(ki % 3 + wo - 1);
        const float m  = 1.0f / (1.0f + __expf(-om[2 * Kn + ki]));
        const float y0f = floorf(py), x0f = floorf(px);
        const float ly = py - y0f, lx = px - x0f;
        const int iy0 = (int)y0f, ix0 = (int)x0f;
        const int iy1 = iy0 + 1,  ix1 = ix0 + 1;
        const float vy0 = (iy0 >= 0 && iy0 < Hn) ? 1.0f : 0.0f;
        const float vy1 = (iy1 >= 0 && iy1 < Hn) ? 1.0f : 0.0f;
        const float vx0 = (ix0 >= 0 && ix0 < Wn) ? 1.0f : 0.0f;
        const float vx1 = (ix1 >= 0 && ix1 < Wn) ? 1.0f : 0.0f;
        const int iy0c = min(max(iy0, 0), Hn - 1);
        const int iy1c = min(max(iy1, 0), Hn - 1);
        const int ix0c = min(max(ix0, 0), Wn - 1);
        const int ix1c = min(max(ix1, 0), Wn - 1);
        pw0[ki] = m * (1.0f - ly) * (1.0f - lx) * vy0 * vx0;
        pw1[ki] = m * (1.0f - ly) * lx          * vy0 * vx1;
        pw2[ki] = m * ly          * (1.0f - lx) * vy1 * vx0;
        pw3[ki] = m * ly          * lx          * vy1 * vx1;
        pa[ki]   = iy0c * Wn + ix0c;
        pdx[ki]  = ix1c - ix0c;
        pdyw[ki] = (iy1c - iy0c) * Wn;
    }
    float acc[OCn];
#pragma unroll
    for (int oc = 0; oc < OCn; ++oc) acc[oc] = bias[oc];
    for (int c = 0; c < Cn; ++c) {
        const float* xc = xb + c * HWn;
        float s[Kn];
#pragma unroll
        for (int ki = 0; ki < Kn; ++ki) {
            const float* bp = xc + pa[ki];
            s[ki] = pw0[ki] * bp[0] + pw1[ki] * bp[pdx[ki]]
                  + pw2[ki] * bp[pdyw[ki]] + pw3[ki] * bp[pdyw[ki] + pdx[ki]];
        }
        const float* wc = weight + c * Kn;
#pragma unroll
        for (int oc = 0; oc < OCn; ++oc) {
            const float* wp = wc + oc * (Cn * Kn);
            float a = acc[oc];
#pragma unroll
            for (int ki = 0; ki < Kn; ++ki) a = fmaf(s[ki], wp[ki], a);
            acc[oc] = a;
        }
    }
    float* ob = out + b * (OCn * HWn) + hw;
#pragma unroll
    for (int oc = 0; oc < OCn; ++oc) ob[oc * HWn] = acc[oc];
}

extern "C" void kernel_launch(void* const* d_in, const int* in_sizes, int n_in,
                              void* d_out, int out_size, void* d_ws, size_t ws_size,
                              hipStream_t stream) {
    const float* x      = (const float*)d_in[0];
    const float* w_off  = (const float*)d_in[1];
    const float* b_off  = (const float*)d_in[2];
    const float* weight = (const float*)d_in[3];
    const float* bias   = (const float*)d_in[4];
    float* out = (float*)d_out;

    if (ws_size >= WS_BYTES) {
        float* pwbuf = (float*)d_ws;
        int*   abuf  = (int*)((float*)d_ws + 36 * NPIX);
        hipLaunchKernelGGL(dcn_k1, dim3(PGRPS), dim3(256), 0, stream,
                           x, w_off, b_off, bias, out, pwbuf, abuf);
        hipLaunchKernelGGL(dcn_k2, dim3(PGRPS * 2), dim3(256), 0, stream,
                           x, weight, pwbuf, abuf, out);
    } else {
        hipLaunchKernelGGL(dcn_r1, dim3(NPIX / 64), dim3(64), 0, stream,
                           x, w_off, b_off, weight, bias, out);
    }
}

// Round 5
// 596.688 us; speedup vs baseline: 5.7296x; 5.7296x over previous
//
#include <hip/hip_runtime.h>
#include <math.h>

#define Bn 8
#define Cn 64
#define Hn 96
#define Wn 96
#define HWn (Hn*Wn)
#define OCn 64
#define Kn 9
#define OFFCn 27
#define NPIX (Bn*HWn)        // 73728 = 1152*64
#define PGRPS (NPIX/64)      // 1152 pixel groups

// ws layout: float pwbuf[4][9][NPIX] then int abuf[9][NPIX] = 45*NPIX dwords
#define WS_DWORDS (45*NPIX)
#define WS_BYTES  ((size_t)WS_DWORDS*4)   // 13.27 MB

// ============================ K1: offset conv + sampling params ===============
__global__ __launch_bounds__(256, 2) void dcn_k1(
    const float* __restrict__ x,
    const float* __restrict__ w_off,
    const float* __restrict__ b_off,
    float* __restrict__ pwbuf,
    int*   __restrict__ abuf)
{
    __shared__ float lds[4 * 64 * OFFCn];   // 27.6 KB

    const int tid  = threadIdx.x;
    const int lane = tid & 63;
    const int wv   = tid >> 6;
    const int cbase = __builtin_amdgcn_readfirstlane(wv * 16);  // uniform -> s_loads

    const int p  = blockIdx.x * 64 + lane;
    const int b  = p / HWn;
    const int hw = p % HWn;
    const int ho = hw / Wn;
    const int wo = hw % Wn;

    const float* xb = x + b * (Cn * HWn);

    // static 3x3 taps, zero-pad via multiply (branchless, uniform CF)
    int   toff[Kn];
    float tval[Kn];
#pragma unroll
    for (int ki = 0; ki < Kn; ++ki) {
        const int yy = ho + ki / 3 - 1, xx = wo + ki % 3 - 1;
        const bool v = (yy >= 0) && (yy < Hn) && (xx >= 0) && (xx < Wn);
        toff[ki] = min(max(yy, 0), Hn - 1) * Wn + min(max(xx, 0), Wn - 1);
        tval[ki] = v ? 1.0f : 0.0f;
    }

    // offset conv partial over 16 channels per wave
    float om[OFFCn];
#pragma unroll
    for (int j = 0; j < OFFCn; ++j) om[j] = 0.0f;

    for (int ci = 0; ci < 16; ++ci) {
        const int c = cbase + ci;
        const float* xc = xb + c * HWn;
        float xk[Kn];
#pragma unroll
        for (int ki = 0; ki < Kn; ++ki)
            xk[ki] = xc[toff[ki]] * tval[ki];

        const float* wc = w_off + c * Kn;          // w_off[och][c][0..8]
#pragma unroll
        for (int och = 0; och < OFFCn; ++och) {
            const float* wp = wc + och * (Cn * Kn);
            float a = om[och];
#pragma unroll
            for (int ki = 0; ki < Kn; ++ki)
                a = fmaf(xk[ki], wp[ki], a);
            om[och] = a;
        }
    }

    // LDS reduce (stride 27 dwords, gcd(27,32)=1 -> conflict-free)
#pragma unroll
    for (int j = 0; j < OFFCn; ++j)
        lds[(wv * 64 + lane) * OFFCn + j] = om[j];
    __syncthreads();
#pragma unroll
    for (int j = 0; j < OFFCn; ++j) {
        float a = b_off[j];
#pragma unroll
        for (int ww = 0; ww < 4; ++ww)
            a += lds[(ww * 64 + lane) * OFFCn + j];
        om[j] = a;
    }

    // per-k sampling params (each wave computes redundantly; stores its slice)
    float pw0[Kn], pw1[Kn], pw2[Kn], pw3[Kn];
    int   pav[Kn];
#pragma unroll
    for (int ki = 0; ki < Kn; ++ki) {
        const float py = om[ki]      + (float)(ki / 3 + ho - 1);
        const float px = om[Kn + ki] + (float)(ki % 3 + wo - 1);
        const float m  = 1.0f / (1.0f + __expf(-om[2 * Kn + ki]));

        const float y0f = floorf(py), x0f = floorf(px);
        const float ly = py - y0f, lx = px - x0f;
        const int iy0 = (int)y0f, ix0 = (int)x0f;
        const int iy1 = iy0 + 1,  ix1 = ix0 + 1;

        const float vy0 = (iy0 >= 0 && iy0 < Hn) ? 1.0f : 0.0f;
        const float vy1 = (iy1 >= 0 && iy1 < Hn) ? 1.0f : 0.0f;
        const float vx0 = (ix0 >= 0 && ix0 < Wn) ? 1.0f : 0.0f;
        const float vx1 = (ix1 >= 0 && ix1 < Wn) ? 1.0f : 0.0f;

        const int iy0c = min(max(iy0, 0), Hn - 1);
        const int iy1c = min(max(iy1, 0), Hn - 1);
        const int ix0c = min(max(ix0, 0), Wn - 1);
        const int ix1c = min(max(ix1, 0), Wn - 1);

        pw0[ki] = m * (1.0f - ly) * (1.0f - lx) * vy0 * vx0;
        pw1[ki] = m * (1.0f - ly) * lx          * vy0 * vx1;
        pw2[ki] = m * ly          * (1.0f - lx) * vy1 * vx0;
        pw3[ki] = m * ly          * lx          * vy1 * vx1;
        const int pa  = iy0c * Wn + ix0c;        // <= 9215, fits 16 bits
        const int dx  = ix1c - ix0c;             // 0/1
        const int dyw = (iy1c - iy0c) * Wn;      // 0/96
        pav[ki] = pa | (dx << 16) | (dyw << 17);
    }

    if (wv == 0) {
#pragma unroll
        for (int ki = 0; ki < Kn; ++ki) pwbuf[(0 * Kn + ki) * NPIX + p] = pw0[ki];
#pragma unroll
        for (int ki = 0; ki < Kn; ++ki) abuf[ki * NPIX + p] = pav[ki];
    } else if (wv == 1) {
#pragma unroll
        for (int ki = 0; ki < Kn; ++ki) pwbuf[(1 * Kn + ki) * NPIX + p] = pw1[ki];
    } else if (wv == 2) {
#pragma unroll
        for (int ki = 0; ki < Kn; ++ki) pwbuf[(2 * Kn + ki) * NPIX + p] = pw2[ki];
    } else {
#pragma unroll
        for (int ki = 0; ki < Kn; ++ki) pwbuf[(3 * Kn + ki) * NPIX + p] = pw3[ki];
    }
}

// ============================ K2: sample + contract (oc-split, no atomics) ====
__global__ __launch_bounds__(256, 2) void dcn_k2(
    const float* __restrict__ x,
    const float* __restrict__ weight,
    const float* __restrict__ bias,
    const float* __restrict__ pwbuf,
    const int*   __restrict__ abuf,
    float* __restrict__ out)
{
    const int tid  = threadIdx.x;
    const int lane = tid & 63;
    const int ocb  = __builtin_amdgcn_readfirstlane((tid >> 6) * 16); // 0/16/32/48

    const int p  = blockIdx.x * 64 + lane;
    const int b  = p / HWn;
    const int hw = p % HWn;

    const float* xb = x + b * (Cn * HWn);

    // load params (coalesced dword streams)
    float pw0[Kn], pw1[Kn], pw2[Kn], pw3[Kn];
    int   pa[Kn], pdx[Kn], pdyw[Kn];
#pragma unroll
    for (int ki = 0; ki < Kn; ++ki) pw0[ki] = pwbuf[(0 * Kn + ki) * NPIX + p];
#pragma unroll
    for (int ki = 0; ki < Kn; ++ki) pw1[ki] = pwbuf[(1 * Kn + ki) * NPIX + p];
#pragma unroll
    for (int ki = 0; ki < Kn; ++ki) pw2[ki] = pwbuf[(2 * Kn + ki) * NPIX + p];
#pragma unroll
    for (int ki = 0; ki < Kn; ++ki) pw3[ki] = pwbuf[(3 * Kn + ki) * NPIX + p];
#pragma unroll
    for (int ki = 0; ki < Kn; ++ki) {
        const int av = abuf[ki * NPIX + p];
        pa[ki]   = av & 0xFFFF;
        pdx[ki]  = (av >> 16) & 1;
        pdyw[ki] = av >> 17;
    }

    float acc[16];
#pragma unroll
    for (int j = 0; j < 16; ++j) acc[j] = bias[ocb + j];   // scalar loads

    for (int c = 0; c < Cn; ++c) {
        const float* xc = xb + c * HWn;
        float s[Kn];
#pragma unroll
        for (int ki = 0; ki < Kn; ++ki) {
            const float* bp = xc + pa[ki];
            const float v00 = bp[0];
            const float v01 = bp[pdx[ki]];
            const float v10 = bp[pdyw[ki]];
            const float v11 = bp[pdyw[ki] + pdx[ki]];
            s[ki] = pw0[ki] * v00 + pw1[ki] * v01 + pw2[ki] * v10 + pw3[ki] * v11;
        }

        const float* wc = weight + (ocb * Cn + c) * Kn;    // uniform -> s_load
#pragma unroll
        for (int j = 0; j < 16; ++j) {
            const float* wp = wc + j * (Cn * Kn);
            float a = acc[j];
#pragma unroll
            for (int ki = 0; ki < Kn; ++ki)
                a = fmaf(s[ki], wp[ki], a);
            acc[j] = a;
        }
    }

    float* ob = out + b * (OCn * HWn) + hw;
#pragma unroll
    for (int j = 0; j < 16; ++j)
        ob[(ocb + j) * HWn] = acc[j];
}

// ============================ fallback (R1 single-kernel, if ws too small) ====
__global__ __launch_bounds__(64) void dcn_r1(
    const float* __restrict__ x,
    const float* __restrict__ w_off,
    const float* __restrict__ b_off,
    const float* __restrict__ weight,
    const float* __restrict__ bias,
    float* __restrict__ out)
{
    const int p  = blockIdx.x * 64 + threadIdx.x;
    const int b  = p / HWn;
    const int hw = p % HWn;
    const int ho = hw / Wn;
    const int wo = hw % Wn;
    const float* xb = x + b * (Cn * HWn);

    float om[OFFCn];
#pragma unroll
    for (int j = 0; j < OFFCn; ++j) om[j] = b_off[j];

    int   toff[Kn];
    float tval[Kn];
#pragma unroll
    for (int ki = 0; ki < Kn; ++ki) {
        const int yy = ho + ki / 3 - 1, xx = wo + ki % 3 - 1;
        const bool v = (yy >= 0) && (yy < Hn) && (xx >= 0) && (xx < Wn);
        toff[ki] = min(max(yy, 0), Hn - 1) * Wn + min(max(xx, 0), Wn - 1);
        tval[ki] = v ? 1.0f : 0.0f;
    }
    for (int c = 0; c < Cn; ++c) {
        const float* xc = xb + c * HWn;
        float xk[Kn];
#pragma unroll
        for (int ki = 0; ki < Kn; ++ki) xk[ki] = xc[toff[ki]] * tval[ki];
        const float* wc = w_off + c * Kn;
#pragma unroll
        for (int och = 0; och < OFFCn; ++och) {
            const float* wp = wc + och * (Cn * Kn);
            float a = om[och];
#pragma unroll
            for (int ki = 0; ki < Kn; ++ki) a = fmaf(xk[ki], wp[ki], a);
            om[och] = a;
        }
    }
    float pw0[Kn], pw1[Kn], pw2[Kn], pw3[Kn];
    int   pa[Kn], pdx[Kn], pdyw[Kn];
#pragma unroll
    for (int ki = 0; ki < Kn; ++ki) {
        const float py = om[ki]      + (float)(ki / 3 + ho - 1);
        const float px = om[Kn + ki] + (float)(ki % 3 + wo - 1);
        const float m  = 1.0f / (1.0f + __expf(-om[2 * Kn + ki]));
        const float y0f = floorf(py), x0f = floorf(px);
        const float ly = py - y0f, lx = px - x0f;
        const int iy0 = (int)y0f, ix0 = (int)x0f;
        const int iy1 = iy0 + 1,  ix1 = ix0 + 1;
        const float vy0 = (iy0 >= 0 && iy0 < Hn) ? 1.0f : 0.0f;
        const float vy1 = (iy1 >= 0 && iy1 < Hn) ? 1.0f : 0.0f;
        const float vx0 = (ix0 >= 0 && ix0 < Wn) ? 1.0f : 0.0f;
        const float vx1 = (ix1 >= 0 && ix1 < Wn) ? 1.0f : 0.0f;
        const int iy0c = min(max(iy0, 0), Hn - 1);
        const int iy1c = min(max(iy1, 0), Hn - 1);
        const int ix0c = min(max(ix0, 0), Wn - 1);
        const int ix1c = min(max(ix1, 0), Wn - 1);
        pw0[ki] = m * (1.0f - ly) * (1.0f - lx) * vy0 * vx0;
        pw1[ki] = m * (1.0f - ly) * lx          * vy0 * vx1;
        pw2[ki] = m * ly          * (1.0f - lx) * vy1 * vx0;
        pw3[ki] = m * ly          * lx          * vy1 * vx1;
        pa[ki]   = iy0c * Wn + ix0c;
        pdx[ki]  = ix1c - ix0c;
        pdyw[ki] = (iy1c - iy0c) * Wn;
    }
    float acc[OCn];
#pragma unroll
    for (int oc = 0; oc < OCn; ++oc) acc[oc] = bias[oc];
    for (int c = 0; c < Cn; ++c) {
        const float* xc = xb + c * HWn;
        float s[Kn];
#pragma unroll
        for (int ki = 0; ki < Kn; ++ki) {
            const float* bp = xc + pa[ki];
            s[ki] = pw0[ki] * bp[0] + pw1[ki] * bp[pdx[ki]]
                  + pw2[ki] * bp[pdyw[ki]] + pw3[ki] * bp[pdyw[ki] + pdx[ki]];
        }
        const float* wc = weight + c * Kn;
#pragma unroll
        for (int oc = 0; oc < OCn; ++oc) {
            const float* wp = wc + oc * (Cn * Kn);
            float a = acc[oc];
#pragma unroll
            for (int ki = 0; ki < Kn; ++ki) a = fmaf(s[ki], wp[ki], a);
            acc[oc] = a;
        }
    }
    float* ob = out + b * (OCn * HWn) + hw;
#pragma unroll
    for (int oc = 0; oc < OCn; ++oc) ob[oc * HWn] = acc[oc];
}

extern "C" void kernel_launch(void* const* d_in, const int* in_sizes, int n_in,
                              void* d_out, int out_size, void* d_ws, size_t ws_size,
                              hipStream_t stream) {
    const float* x      = (const float*)d_in[0];
    const float* w_off  = (const float*)d_in[1];
    const float* b_off  = (const float*)d_in[2];
    const float* weight = (const float*)d_in[3];
    const float* bias   = (const float*)d_in[4];
    float* out = (float*)d_out;

    if (ws_size >= WS_BYTES) {
        float* pwbuf = (float*)d_ws;
        int*   abuf  = (int*)((float*)d_ws + 36 * NPIX);
        hipLaunchKernelGGL(dcn_k1, dim3(PGRPS), dim3(256), 0, stream,
                           x, w_off, b_off, pwbuf, abuf);
        hipLaunchKernelGGL(dcn_k2, dim3(PGRPS), dim3(256), 0, stream,
                           x, weight, bias, pwbuf, abuf, out);
    } else {
        hipLaunchKernelGGL(dcn_r1, dim3(NPIX / 64), dim3(64), 0, stream,
                           x, w_off, b_off, weight, bias, out);
    }
}

// Round 6
// 356.100 us; speedup vs baseline: 9.6007x; 1.6756x over previous
//
#include <hip/hip_runtime.h>
#include <math.h>

#define Bn 8
#define Cn 64
#define Hn 96
#define Wn 96
#define HWn (Hn*Wn)
#define OCn 64
#define Kn 9
#define OFFCn 27
#define NPIX (Bn*HWn)        // 73728 = 1152*64
#define PGRPS (NPIX/64)      // 1152 pixel groups

// ws layout: float pwbuf[4][9][NPIX] then int abuf[9][NPIX] = 45*NPIX dwords
#define WS_DWORDS (45*NPIX)
#define WS_BYTES  ((size_t)WS_DWORDS*4)   // 13.27 MB

// ============================ K1: offset conv + sampling params ===============
__global__ __launch_bounds__(256, 2) void dcn_k1(
    const float* __restrict__ x,
    const float* __restrict__ w_off,
    const float* __restrict__ b_off,
    float* __restrict__ pwbuf,
    int*   __restrict__ abuf)
{
    __shared__ float lds[4 * 64 * OFFCn];   // 27.6 KB

    const int tid  = threadIdx.x;
    const int lane = tid & 63;
    const int wv   = tid >> 6;
    const int cbase = __builtin_amdgcn_readfirstlane(wv * 16);  // uniform -> s_loads

    const int p  = blockIdx.x * 64 + lane;
    const int b  = p / HWn;
    const int hw = p % HWn;
    const int ho = hw / Wn;
    const int wo = hw % Wn;

    const float* xb = x + b * (Cn * HWn);

    // static 3x3 taps, zero-pad via multiply (branchless, uniform CF)
    int   toff[Kn];
    float tval[Kn];
#pragma unroll
    for (int ki = 0; ki < Kn; ++ki) {
        const int yy = ho + ki / 3 - 1, xx = wo + ki % 3 - 1;
        const bool v = (yy >= 0) && (yy < Hn) && (xx >= 0) && (xx < Wn);
        toff[ki] = min(max(yy, 0), Hn - 1) * Wn + min(max(xx, 0), Wn - 1);
        tval[ki] = v ? 1.0f : 0.0f;
    }

    // offset conv partial over 16 channels per wave
    float om[OFFCn];
#pragma unroll
    for (int j = 0; j < OFFCn; ++j) om[j] = 0.0f;

    for (int ci = 0; ci < 16; ++ci) {
        const int c = cbase + ci;
        const float* xc = xb + c * HWn;
        float xk[Kn];
#pragma unroll
        for (int ki = 0; ki < Kn; ++ki)
            xk[ki] = xc[toff[ki]] * tval[ki];

        const float* wc = w_off + c * Kn;          // w_off[och][c][0..8]
#pragma unroll
        for (int och = 0; och < OFFCn; ++och) {
            const float* wp = wc + och * (Cn * Kn);
            float a = om[och];
#pragma unroll
            for (int ki = 0; ki < Kn; ++ki)
                a = fmaf(xk[ki], wp[ki], a);
            om[och] = a;
        }
    }

    // LDS reduce (stride 27 dwords, gcd(27,32)=1 -> conflict-free)
#pragma unroll
    for (int j = 0; j < OFFCn; ++j)
        lds[(wv * 64 + lane) * OFFCn + j] = om[j];
    __syncthreads();
#pragma unroll
    for (int j = 0; j < OFFCn; ++j) {
        float a = b_off[j];
#pragma unroll
        for (int ww = 0; ww < 4; ++ww)
            a += lds[(ww * 64 + lane) * OFFCn + j];
        om[j] = a;
    }

    // per-k sampling params (each wave computes redundantly; stores its slice)
    float pw0[Kn], pw1[Kn], pw2[Kn], pw3[Kn];
    int   pav[Kn];
#pragma unroll
    for (int ki = 0; ki < Kn; ++ki) {
        const float py = om[ki]      + (float)(ki / 3 + ho - 1);
        const float px = om[Kn + ki] + (float)(ki % 3 + wo - 1);
        const float m  = 1.0f / (1.0f + __expf(-om[2 * Kn + ki]));

        const float y0f = floorf(py), x0f = floorf(px);
        const float ly = py - y0f, lx = px - x0f;
        const int iy0 = (int)y0f, ix0 = (int)x0f;
        const int iy1 = iy0 + 1,  ix1 = ix0 + 1;

        const float vy0 = (iy0 >= 0 && iy0 < Hn) ? 1.0f : 0.0f;
        const float vy1 = (iy1 >= 0 && iy1 < Hn) ? 1.0f : 0.0f;
        const float vx0 = (ix0 >= 0 && ix0 < Wn) ? 1.0f : 0.0f;
        const float vx1 = (ix1 >= 0 && ix1 < Wn) ? 1.0f : 0.0f;

        const int iy0c = min(max(iy0, 0), Hn - 1);
        const int iy1c = min(max(iy1, 0), Hn - 1);
        const int ix0c = min(max(ix0, 0), Wn - 1);
        const int ix1c = min(max(ix1, 0), Wn - 1);

        pw0[ki] = m * (1.0f - ly) * (1.0f - lx) * vy0 * vx0;
        pw1[ki] = m * (1.0f - ly) * lx          * vy0 * vx1;
        pw2[ki] = m * ly          * (1.0f - lx) * vy1 * vx0;
        pw3[ki] = m * ly          * lx          * vy1 * vx1;
        const int pa  = iy0c * Wn + ix0c;        // <= 9215, fits 16 bits
        const int dx  = ix1c - ix0c;             // 0/1
        const int dyw = (iy1c - iy0c) * Wn;      // 0/96
        pav[ki] = pa | (dx << 16) | (dyw << 17);
    }

    if (wv == 0) {
#pragma unroll
        for (int ki = 0; ki < Kn; ++ki) pwbuf[(0 * Kn + ki) * NPIX + p] = pw0[ki];
#pragma unroll
        for (int ki = 0; ki < Kn; ++ki) abuf[ki * NPIX + p] = pav[ki];
    } else if (wv == 1) {
#pragma unroll
        for (int ki = 0; ki < Kn; ++ki) pwbuf[(1 * Kn + ki) * NPIX + p] = pw1[ki];
    } else if (wv == 2) {
#pragma unroll
        for (int ki = 0; ki < Kn; ++ki) pwbuf[(2 * Kn + ki) * NPIX + p] = pw2[ki];
    } else {
#pragma unroll
        for (int ki = 0; ki < Kn; ++ki) pwbuf[(3 * Kn + ki) * NPIX + p] = pw3[ki];
    }
}

// ============ K2: LDS-shared sampling + oc-split contraction (no atomics) =====
// 8-channel chunks: smp = 8*9*64 floats = 18.4 KB -> LDS allows 8 blocks/CU;
// sampling computed ONCE per pixel (was 4x redundant in R5: 679M -> 170M gathers).
__global__ __launch_bounds__(256, 2) void dcn_k2(
    const float* __restrict__ x,
    const float* __restrict__ weight,
    const float* __restrict__ bias,
    const float* __restrict__ pwbuf,
    const int*   __restrict__ abuf,
    float* __restrict__ out)
{
    __shared__ float smp[8 * Kn * 64];   // [c8][ki][pix]

    const int tid  = threadIdx.x;
    const int lane = tid & 63;
    const int wv   = tid >> 6;
    const int ocb  = __builtin_amdgcn_readfirstlane(wv * 16); // 0/16/32/48

    const int p  = blockIdx.x * 64 + lane;
    const int b  = p / HWn;
    const int hw = p % HWn;

    const float* xb = x + b * (Cn * HWn);

    // load params (coalesced dword streams)
    float pw0[Kn], pw1[Kn], pw2[Kn], pw3[Kn];
    int   pa[Kn], pdx[Kn], pdyw[Kn];
#pragma unroll
    for (int ki = 0; ki < Kn; ++ki) pw0[ki] = pwbuf[(0 * Kn + ki) * NPIX + p];
#pragma unroll
    for (int ki = 0; ki < Kn; ++ki) pw1[ki] = pwbuf[(1 * Kn + ki) * NPIX + p];
#pragma unroll
    for (int ki = 0; ki < Kn; ++ki) pw2[ki] = pwbuf[(2 * Kn + ki) * NPIX + p];
#pragma unroll
    for (int ki = 0; ki < Kn; ++ki) pw3[ki] = pwbuf[(3 * Kn + ki) * NPIX + p];
#pragma unroll
    for (int ki = 0; ki < Kn; ++ki) {
        const int av = abuf[ki * NPIX + p];
        pa[ki]   = av & 0xFFFF;
        pdx[ki]  = (av >> 16) & 1;
        pdyw[ki] = av >> 17;
    }

    float acc[16];
#pragma unroll
    for (int j = 0; j < 16; ++j) acc[j] = bias[ocb + j];   // scalar loads

    for (int ch = 0; ch < 8; ++ch) {
        // gather: wave wv samples channels ch*8 + wv*2 + {0,1} for its pixel
#pragma unroll
        for (int cc = 0; cc < 2; ++cc) {
            const int cl = wv * 2 + cc;
            const float* xc = xb + (ch * 8 + cl) * HWn;
#pragma unroll
            for (int ki = 0; ki < Kn; ++ki) {
                const float* bp = xc + pa[ki];
                const float v00 = bp[0];
                const float v01 = bp[pdx[ki]];
                const float v10 = bp[pdyw[ki]];
                const float v11 = bp[pdyw[ki] + pdx[ki]];
                smp[(cl * Kn + ki) * 64 + lane] =
                    pw0[ki] * v00 + pw1[ki] * v01 + pw2[ki] * v10 + pw3[ki] * v11;
            }
        }
        __syncthreads();

        const float* wch = weight + (ocb * Cn + ch * 8) * Kn;   // wave-uniform
#pragma unroll 2
        for (int c8 = 0; c8 < 8; ++c8) {
            float sv[Kn];
#pragma unroll
            for (int ki = 0; ki < Kn; ++ki)
                sv[ki] = smp[(c8 * Kn + ki) * 64 + lane];
#pragma unroll
            for (int j = 0; j < 16; ++j) {
                const float* wp = wch + j * (Cn * Kn) + c8 * Kn;
                float a = acc[j];
#pragma unroll
                for (int ki = 0; ki < Kn; ++ki)
                    a = fmaf(sv[ki], wp[ki], a);
                acc[j] = a;
            }
        }
        __syncthreads();
    }

    float* ob = out + b * (OCn * HWn) + hw;
#pragma unroll
    for (int j = 0; j < 16; ++j)
        ob[(ocb + j) * HWn] = acc[j];
}

// ============================ fallback (R1 single-kernel, if ws too small) ====
__global__ __launch_bounds__(64) void dcn_r1(
    const float* __restrict__ x,
    const float* __restrict__ w_off,
    const float* __restrict__ b_off,
    const float* __restrict__ weight,
    const float* __restrict__ bias,
    float* __restrict__ out)
{
    const int p  = blockIdx.x * 64 + threadIdx.x;
    const int b  = p / HWn;
    const int hw = p % HWn;
    const int ho = hw / Wn;
    const int wo = hw % Wn;
    const float* xb = x + b * (Cn * HWn);

    float om[OFFCn];
#pragma unroll
    for (int j = 0; j < OFFCn; ++j) om[j] = b_off[j];

    int   toff[Kn];
    float tval[Kn];
#pragma unroll
    for (int ki = 0; ki < Kn; ++ki) {
        const int yy = ho + ki / 3 - 1, xx = wo + ki % 3 - 1;
        const bool v = (yy >= 0) && (yy < Hn) && (xx >= 0) && (xx < Wn);
        toff[ki] = min(max(yy, 0), Hn - 1) * Wn + min(max(xx, 0), Wn - 1);
        tval[ki] = v ? 1.0f : 0.0f;
    }
    for (int c = 0; c < Cn; ++c) {
        const float* xc = xb + c * HWn;
        float xk[Kn];
#pragma unroll
        for (int ki = 0; ki < Kn; ++ki) xk[ki] = xc[toff[ki]] * tval[ki];
        const float* wc = w_off + c * Kn;
#pragma unroll
        for (int och = 0; och < OFFCn; ++och) {
            const float* wp = wc + och * (Cn * Kn);
            float a = om[och];
#pragma unroll
            for (int ki = 0; ki < Kn; ++ki) a = fmaf(xk[ki], wp[ki], a);
            om[och] = a;
        }
    }
    float pw0[Kn], pw1[Kn], pw2[Kn], pw3[Kn];
    int   pa[Kn], pdx[Kn], pdyw[Kn];
#pragma unroll
    for (int ki = 0; ki < Kn; ++ki) {
        const float py = om[ki]      + (float)(ki / 3 + ho - 1);
        const float px = om[Kn + ki] + (float)(ki % 3 + wo - 1);
        const float m  = 1.0f / (1.0f + __expf(-om[2 * Kn + ki]));
        const float y0f = floorf(py), x0f = floorf(px);
        const float ly = py - y0f, lx = px - x0f;
        const int iy0 = (int)y0f, ix0 = (int)x0f;
        const int iy1 = iy0 + 1,  ix1 = ix0 + 1;
        const float vy0 = (iy0 >= 0 && iy0 < Hn) ? 1.0f : 0.0f;
        const float vy1 = (iy1 >= 0 && iy1 < Hn) ? 1.0f : 0.0f;
        const float vx0 = (ix0 >= 0 && ix0 < Wn) ? 1.0f : 0.0f;
        const float vx1 = (ix1 >= 0 && ix1 < Wn) ? 1.0f : 0.0f;
        const int iy0c = min(max(iy0, 0), Hn - 1);
        const int iy1c = min(max(iy1, 0), Hn - 1);
        const int ix0c = min(max(ix0, 0), Wn - 1);
        const int ix1c = min(max(ix1, 0), Wn - 1);
        pw0[ki] = m * (1.0f - ly) * (1.0f - lx) * vy0 * vx0;
        pw1[ki] = m * (1.0f - ly) * lx          * vy0 * vx1;
        pw2[ki] = m * ly          * (1.0f - lx) * vy1 * vx0;
        pw3[ki] = m * ly          * lx          * vy1 * vx1;
        pa[ki]   = iy0c * Wn + ix0c;
        pdx[ki]  = ix1c - ix0c;
        pdyw[ki] = (iy1c - iy0c) * Wn;
    }
    float acc[OCn];
#pragma unroll
    for (int oc = 0; oc < OCn; ++oc) acc[oc] = bias[oc];
    for (int c = 0; c < Cn; ++c) {
        const float* xc = xb + c * HWn;
        float s[Kn];
#pragma unroll
        for (int ki = 0; ki < Kn; ++ki) {
            const float* bp = xc + pa[ki];
            s[ki] = pw0[ki] * bp[0] + pw1[ki] * bp[pdx[ki]]
                  + pw2[ki] * bp[pdyw[ki]] + pw3[ki] * bp[pdyw[ki] + pdx[ki]];
        }
        const float* wc = weight + c * Kn;
#pragma unroll
        for (int oc = 0; oc < OCn; ++oc) {
            const float* wp = wc + oc * (Cn * Kn);
            float a = acc[oc];
#pragma unroll
            for (int ki = 0; ki < Kn; ++ki) a = fmaf(s[ki], wp[ki], a);
            acc[oc] = a;
        }
    }
    float* ob = out + b * (OCn * HWn) + hw;
#pragma unroll
    for (int oc = 0; oc < OCn; ++oc) ob[oc * HWn] = acc[oc];
}

extern "C" void kernel_launch(void* const* d_in, const int* in_sizes, int n_in,
                              void* d_out, int out_size, void* d_ws, size_t ws_size,
                              hipStream_t stream) {
    const float* x      = (const float*)d_in[0];
    const float* w_off  = (const float*)d_in[1];
    const float* b_off  = (const float*)d_in[2];
    const float* weight = (const float*)d_in[3];
    const float* bias   = (const float*)d_in[4];
    float* out = (float*)d_out;

    if (ws_size >= WS_BYTES) {
        float* pwbuf = (float*)d_ws;
        int*   abuf  = (int*)((float*)d_ws + 36 * NPIX);
        hipLaunchKernelGGL(dcn_k1, dim3(PGRPS), dim3(256), 0, stream,
                           x, w_off, b_off, pwbuf, abuf);
        hipLaunchKernelGGL(dcn_k2, dim3(PGRPS), dim3(256), 0, stream,
                           x, weight, bias, pwbuf, abuf, out);
    } else {
        hipLaunchKernelGGL(dcn_r1, dim3(NPIX / 64), dim3(64), 0, stream,
                           x, w_off, b_off, weight, bias, out);
    }
}

// Round 7
// 283.364 us; speedup vs baseline: 12.0651x; 1.2567x over previous
//
#include <hip/hip_runtime.h>
#include <math.h>

#define Bn 8
#define Cn 64
#define Hn 96
#define Wn 96
#define HWn (Hn*Wn)
#define OCn 64
#define Kn 9
#define OFFCn 27
#define NPIX (Bn*HWn)        // 73728 = 1152*64
#define PGRPS (NPIX/64)      // 1152 pixel groups

// ws layout: float pwbuf[4][9][NPIX] then int abuf[9][NPIX] = 45*NPIX dwords
#define WS_DWORDS (45*NPIX)
#define WS_BYTES  ((size_t)WS_DWORDS*4)   // 13.27 MB

// ============================ K1: offset conv + sampling params ===============
__global__ __launch_bounds__(256, 2) void dcn_k1(
    const float* __restrict__ x,
    const float* __restrict__ w_off,
    const float* __restrict__ b_off,
    float* __restrict__ pwbuf,
    int*   __restrict__ abuf)
{
    __shared__ float lds[4 * 64 * OFFCn];   // 27.6 KB

    const int tid  = threadIdx.x;
    const int lane = tid & 63;
    const int wv   = tid >> 6;
    const int cbase = __builtin_amdgcn_readfirstlane(wv * 16);  // uniform -> s_loads

    const int p  = blockIdx.x * 64 + lane;
    const int b  = p / HWn;
    const int hw = p % HWn;
    const int ho = hw / Wn;
    const int wo = hw % Wn;

    const float* xb = x + b * (Cn * HWn);

    // static 3x3 taps, zero-pad via multiply (branchless, uniform CF)
    int   toff[Kn];
    float tval[Kn];
#pragma unroll
    for (int ki = 0; ki < Kn; ++ki) {
        const int yy = ho + ki / 3 - 1, xx = wo + ki % 3 - 1;
        const bool v = (yy >= 0) && (yy < Hn) && (xx >= 0) && (xx < Wn);
        toff[ki] = min(max(yy, 0), Hn - 1) * Wn + min(max(xx, 0), Wn - 1);
        tval[ki] = v ? 1.0f : 0.0f;
    }

    // offset conv partial over 16 channels per wave
    float om[OFFCn];
#pragma unroll
    for (int j = 0; j < OFFCn; ++j) om[j] = 0.0f;

    for (int ci = 0; ci < 16; ++ci) {
        const int c = cbase + ci;
        const float* xc = xb + c * HWn;
        float xk[Kn];
#pragma unroll
        for (int ki = 0; ki < Kn; ++ki)
            xk[ki] = xc[toff[ki]] * tval[ki];

        const float* wc = w_off + c * Kn;          // w_off[och][c][0..8]
#pragma unroll
        for (int och = 0; och < OFFCn; ++och) {
            const float* wp = wc + och * (Cn * Kn);
            float a = om[och];
#pragma unroll
            for (int ki = 0; ki < Kn; ++ki)
                a = fmaf(xk[ki], wp[ki], a);
            om[och] = a;
        }
    }

    // LDS reduce (stride 27 dwords, gcd(27,32)=1 -> conflict-free)
#pragma unroll
    for (int j = 0; j < OFFCn; ++j)
        lds[(wv * 64 + lane) * OFFCn + j] = om[j];
    __syncthreads();
#pragma unroll
    for (int j = 0; j < OFFCn; ++j) {
        float a = b_off[j];
#pragma unroll
        for (int ww = 0; ww < 4; ++ww)
            a += lds[(ww * 64 + lane) * OFFCn + j];
        om[j] = a;
    }

    // per-k sampling params (each wave computes redundantly; stores its slice)
    float pw0[Kn], pw1[Kn], pw2[Kn], pw3[Kn];
    int   pav[Kn];
#pragma unroll
    for (int ki = 0; ki < Kn; ++ki) {
        const float py = om[ki]      + (float)(ki / 3 + ho - 1);
        const float px = om[Kn + ki] + (float)(ki % 3 + wo - 1);
        const float m  = 1.0f / (1.0f + __expf(-om[2 * Kn + ki]));

        const float y0f = floorf(py), x0f = floorf(px);
        const float ly = py - y0f, lx = px - x0f;
        const int iy0 = (int)y0f, ix0 = (int)x0f;
        const int iy1 = iy0 + 1,  ix1 = ix0 + 1;

        const float vy0 = (iy0 >= 0 && iy0 < Hn) ? 1.0f : 0.0f;
        const float vy1 = (iy1 >= 0 && iy1 < Hn) ? 1.0f : 0.0f;
        const float vx0 = (ix0 >= 0 && ix0 < Wn) ? 1.0f : 0.0f;
        const float vx1 = (ix1 >= 0 && ix1 < Wn) ? 1.0f : 0.0f;

        const int iy0c = min(max(iy0, 0), Hn - 1);
        const int iy1c = min(max(iy1, 0), Hn - 1);
        const int ix0c = min(max(ix0, 0), Wn - 1);
        const int ix1c = min(max(ix1, 0), Wn - 1);

        pw0[ki] = m * (1.0f - ly) * (1.0f - lx) * vy0 * vx0;
        pw1[ki] = m * (1.0f - ly) * lx          * vy0 * vx1;
        pw2[ki] = m * ly          * (1.0f - lx) * vy1 * vx0;
        pw3[ki] = m * ly          * lx          * vy1 * vx1;
        const int pa  = iy0c * Wn + ix0c;        // <= 9215, fits 16 bits
        const int dx  = ix1c - ix0c;             // 0/1
        const int dyw = (iy1c - iy0c) * Wn;      // 0/96
        pav[ki] = pa | (dx << 16) | (dyw << 17);
    }

    if (wv == 0) {
#pragma unroll
        for (int ki = 0; ki < Kn; ++ki) pwbuf[(0 * Kn + ki) * NPIX + p] = pw0[ki];
#pragma unroll
        for (int ki = 0; ki < Kn; ++ki) abuf[ki * NPIX + p] = pav[ki];
    } else if (wv == 1) {
#pragma unroll
        for (int ki = 0; ki < Kn; ++ki) pwbuf[(1 * Kn + ki) * NPIX + p] = pw1[ki];
    } else if (wv == 2) {
#pragma unroll
        for (int ki = 0; ki < Kn; ++ki) pwbuf[(2 * Kn + ki) * NPIX + p] = pw2[ki];
    } else {
#pragma unroll
        for (int ki = 0; ki < Kn; ++ki) pwbuf[(3 * Kn + ki) * NPIX + p] = pw3[ki];
    }
}

// ====== K2: 8-wave, LDS-shared sampling + 8-way oc-split (no atomics) =========
// 512 threads: wave wv gathers channel ch*8+wv per chunk; contracts 8 OCs.
// Per-thread FMA work halves vs R6; per-wave s_load weight stream halves;
// resident waves/CU ~2 blocks x 8 = 16 (VGPR<=128) vs ~9 in R6.
__global__ __launch_bounds__(512, 4) void dcn_k2(
    const float* __restrict__ x,
    const float* __restrict__ weight,
    const float* __restrict__ bias,
    const float* __restrict__ pwbuf,
    const int*   __restrict__ abuf,
    float* __restrict__ out)
{
    __shared__ float smp[8 * Kn * 64];   // [c8][ki][pix] = 18.4 KB

    const int tid  = threadIdx.x;
    const int lane = tid & 63;
    const int wv   = tid >> 6;                                 // 0..7
    const int ocb  = __builtin_amdgcn_readfirstlane(wv * 8);   // 0,8,..,56

    const int p  = blockIdx.x * 64 + lane;
    const int b  = p / HWn;
    const int hw = p % HWn;

    const float* xb = x + b * (Cn * HWn);

    // load params (coalesced dword streams); keep addresses PACKED (reg save)
    float pw0[Kn], pw1[Kn], pw2[Kn], pw3[Kn];
    int   pav[Kn];
#pragma unroll
    for (int ki = 0; ki < Kn; ++ki) pw0[ki] = pwbuf[(0 * Kn + ki) * NPIX + p];
#pragma unroll
    for (int ki = 0; ki < Kn; ++ki) pw1[ki] = pwbuf[(1 * Kn + ki) * NPIX + p];
#pragma unroll
    for (int ki = 0; ki < Kn; ++ki) pw2[ki] = pwbuf[(2 * Kn + ki) * NPIX + p];
#pragma unroll
    for (int ki = 0; ki < Kn; ++ki) pw3[ki] = pwbuf[(3 * Kn + ki) * NPIX + p];
#pragma unroll
    for (int ki = 0; ki < Kn; ++ki) pav[ki] = abuf[ki * NPIX + p];

    float acc[8];
#pragma unroll
    for (int j = 0; j < 8; ++j) acc[j] = bias[ocb + j];   // scalar loads

    for (int ch = 0; ch < 8; ++ch) {
        // gather: wave wv samples channel ch*8 + wv for its pixel (once/pixel)
        {
            const float* xc = xb + (ch * 8 + wv) * HWn;
#pragma unroll
            for (int ki = 0; ki < Kn; ++ki) {
                const int av  = pav[ki];
                const int pa  = av & 0xFFFF;
                const int dx  = (av >> 16) & 1;
                const int dyw = av >> 17;
                const float* bp = xc + pa;
                const float v00 = bp[0];
                const float v01 = bp[dx];
                const float v10 = bp[dyw];
                const float v11 = bp[dyw + dx];
                smp[(wv * Kn + ki) * 64 + lane] =
                    pw0[ki] * v00 + pw1[ki] * v01 + pw2[ki] * v10 + pw3[ki] * v11;
            }
        }
        __syncthreads();

        const float* wch = weight + (ocb * Cn + ch * 8) * Kn;   // wave-uniform
#pragma unroll 2
        for (int c8 = 0; c8 < 8; ++c8) {
            float sv[Kn];
#pragma unroll
            for (int ki = 0; ki < Kn; ++ki)
                sv[ki] = smp[(c8 * Kn + ki) * 64 + lane];
#pragma unroll
            for (int j = 0; j < 8; ++j) {
                const float* wp = wch + j * (Cn * Kn) + c8 * Kn;
                float a = acc[j];
#pragma unroll
                for (int ki = 0; ki < Kn; ++ki)
                    a = fmaf(sv[ki], wp[ki], a);
                acc[j] = a;
            }
        }
        __syncthreads();
    }

    float* ob = out + b * (OCn * HWn) + hw;
#pragma unroll
    for (int j = 0; j < 8; ++j)
        ob[(ocb + j) * HWn] = acc[j];
}

// ============================ fallback (R1 single-kernel, if ws too small) ====
__global__ __launch_bounds__(64) void dcn_r1(
    const float* __restrict__ x,
    const float* __restrict__ w_off,
    const float* __restrict__ b_off,
    const float* __restrict__ weight,
    const float* __restrict__ bias,
    float* __restrict__ out)
{
    const int p  = blockIdx.x * 64 + threadIdx.x;
    const int b  = p / HWn;
    const int hw = p % HWn;
    const int ho = hw / Wn;
    const int wo = hw % Wn;
    const float* xb = x + b * (Cn * HWn);

    float om[OFFCn];
#pragma unroll
    for (int j = 0; j < OFFCn; ++j) om[j] = b_off[j];

    int   toff[Kn];
    float tval[Kn];
#pragma unroll
    for (int ki = 0; ki < Kn; ++ki) {
        const int yy = ho + ki / 3 - 1, xx = wo + ki % 3 - 1;
        const bool v = (yy >= 0) && (yy < Hn) && (xx >= 0) && (xx < Wn);
        toff[ki] = min(max(yy, 0), Hn - 1) * Wn + min(max(xx, 0), Wn - 1);
        tval[ki] = v ? 1.0f : 0.0f;
    }
    for (int c = 0; c < Cn; ++c) {
        const float* xc = xb + c * HWn;
        float xk[Kn];
#pragma unroll
        for (int ki = 0; ki < Kn; ++ki) xk[ki] = xc[toff[ki]] * tval[ki];
        const float* wc = w_off + c * Kn;
#pragma unroll
        for (int och = 0; och < OFFCn; ++och) {
            const float* wp = wc + och * (Cn * Kn);
            float a = om[och];
#pragma unroll
            for (int ki = 0; ki < Kn; ++ki) a = fmaf(xk[ki], wp[ki], a);
            om[och] = a;
        }
    }
    float pw0[Kn], pw1[Kn], pw2[Kn], pw3[Kn];
    int   pa[Kn], pdx[Kn], pdyw[Kn];
#pragma unroll
    for (int ki = 0; ki < Kn; ++ki) {
        const float py = om[ki]      + (float)(ki / 3 + ho - 1);
        const float px = om[Kn + ki] + (float)(ki % 3 + wo - 1);
        const float m  = 1.0f / (1.0f + __expf(-om[2 * Kn + ki]));
        const float y0f = floorf(py), x0f = floorf(px);
        const float ly = py - y0f, lx = px - x0f;
        const int iy0 = (int)y0f, ix0 = (int)x0f;
        const int iy1 = iy0 + 1,  ix1 = ix0 + 1;
        const float vy0 = (iy0 >= 0 && iy0 < Hn) ? 1.0f : 0.0f;
        const float vy1 = (iy1 >= 0 && iy1 < Hn) ? 1.0f : 0.0f;
        const float vx0 = (ix0 >= 0 && ix0 < Wn) ? 1.0f : 0.0f;
        const float vx1 = (ix1 >= 0 && ix1 < Wn) ? 1.0f : 0.0f;
        const int iy0c = min(max(iy0, 0), Hn - 1);
        const int iy1c = min(max(iy1, 0), Hn - 1);
        const int ix0c = min(max(ix0, 0), Wn - 1);
        const int ix1c = min(max(ix1, 0), Wn - 1);
        pw0[ki] = m * (1.0f - ly) * (1.0f - lx) * vy0 * vx0;
        pw1[ki] = m * (1.0f - ly) * lx          * vy0 * vx1;
        pw2[ki] = m * ly          * (1.0f - lx) * vy1 * vx0;
        pw3[ki] = m * ly          * lx          * vy1 * vx1;
        pa[ki]   = iy0c * Wn + ix0c;
        pdx[ki]  = ix1c - ix0c;
        pdyw[ki] = (iy1c - iy0c) * Wn;
    }
    float acc[OCn];
#pragma unroll
    for (int oc = 0; oc < OCn; ++oc) acc[oc] = bias[oc];
    for (int c = 0; c < Cn; ++c) {
        const float* xc = xb + c * HWn;
        float s[Kn];
#pragma unroll
        for (int ki = 0; ki < Kn; ++ki) {
            const float* bp = xc + pa[ki];
            s[ki] = pw0[ki] * bp[0] + pw1[ki] * bp[pdx[ki]]
                  + pw2[ki] * bp[pdyw[ki]] + pw3[ki] * bp[pdyw[ki] + pdx[ki]];
        }
        const float* wc = weight + c * Kn;
#pragma unroll
        for (int oc = 0; oc < OCn; ++oc) {
            const float* wp = wc + oc * (Cn * Kn);
            float a = acc[oc];
#pragma unroll
            for (int ki = 0; ki < Kn; ++ki) a = fmaf(s[ki], wp[ki], a);
            acc[oc] = a;
        }
    }
    float* ob = out + b * (OCn * HWn) + hw;
#pragma unroll
    for (int oc = 0; oc < OCn; ++oc) ob[oc * HWn] = acc[oc];
}

extern "C" void kernel_launch(void* const* d_in, const int* in_sizes, int n_in,
                              void* d_out, int out_size, void* d_ws, size_t ws_size,
                              hipStream_t stream) {
    const float* x      = (const float*)d_in[0];
    const float* w_off  = (const float*)d_in[1];
    const float* b_off  = (const float*)d_in[2];
    const float* weight = (const float*)d_in[3];
    const float* bias   = (const float*)d_in[4];
    float* out = (float*)d_out;

    if (ws_size >= WS_BYTES) {
        float* pwbuf = (float*)d_ws;
        int*   abuf  = (int*)((float*)d_ws + 36 * NPIX);
        hipLaunchKernelGGL(dcn_k1, dim3(PGRPS), dim3(256), 0, stream,
                           x, w_off, b_off, pwbuf, abuf);
        hipLaunchKernelGGL(dcn_k2, dim3(PGRPS), dim3(512), 0, stream,
                           x, weight, bias, pwbuf, abuf, out);
    } else {
        hipLaunchKernelGGL(dcn_r1, dim3(NPIX / 64), dim3(64), 0, stream,
                           x, w_off, b_off, weight, bias, out);
    }
}